// Round 7
// baseline (170.886 us; speedup 1.0000x reference)
//
#include <hip/hip_runtime.h>
#include <math.h>

// HardTripletLoss: B=4096, D=512, labels in [0,64), margin 0.5, scalar fp32 out.
// R7: NO-LDS main loop. Each wave owns one 64x64 upper-triangle tile (2080 wave
// jobs, 520 blocks x 4 independent waves, no __syncthreads anywhere). MFMA
// fragments are loaded straight from global (xhi is 4 MB = L2-resident) into
// registers, double-buffered k+1-ahead -> compiler pipelines with fine vmcnt,
// no barrier ever drains the prefetch. Finalize fused via device done-counter.
//
// ws layout (floats): [0,4096)=hp, [4096,8192)=hn, [8192,12288)=norms,
//                     [12288]=done(int), [16384, +2M ushorts)=xhi (4 MB)

#define NB 4096
#define ND 512
#define NLAB 64
#define NTILE 2080  // 64x64-tile upper triangle: 64*65/2

typedef __attribute__((ext_vector_type(8))) short short8;
typedef __attribute__((ext_vector_type(4))) float f32x4;

__device__ __forceinline__ ushort bf16rn(float f) {
    unsigned u = __float_as_uint(f);
    u += 0x7FFF + ((u >> 16) & 1);  // round-to-nearest-even
    return (ushort)(u >> 16);
}

// One wave per row: fp32->bf16 convert + exact fp32 norm; init hp/hn; zero done.
__global__ __launch_bounds__(256) void k_prep(const float* __restrict__ x,
                                              ushort* __restrict__ xhi,
                                              float* __restrict__ norms,
                                              float* __restrict__ hp,
                                              float* __restrict__ hn,
                                              int* __restrict__ done) {
    const int wave = threadIdx.x >> 6, lane = threadIdx.x & 63;
    const int row = blockIdx.x * 4 + wave;
    const float* p = x + (size_t)row * ND + lane * 8;
    float4 v0 = *(const float4*)p;
    float4 v1 = *(const float4*)(p + 4);
    ushort h[8];
    h[0] = bf16rn(v0.x); h[1] = bf16rn(v0.y); h[2] = bf16rn(v0.z); h[3] = bf16rn(v0.w);
    h[4] = bf16rn(v1.x); h[5] = bf16rn(v1.y); h[6] = bf16rn(v1.z); h[7] = bf16rn(v1.w);
    *(uint4*)(xhi + (size_t)row * ND + lane * 8) = *(const uint4*)h;
    float s = v0.x*v0.x + v0.y*v0.y + v0.z*v0.z + v0.w*v0.w
            + v1.x*v1.x + v1.y*v1.y + v1.z*v1.z + v1.w*v1.w;
    #pragma unroll
    for (int m = 1; m < 64; m <<= 1) s += __shfl_xor(s, m);
    if (lane == 0) norms[row] = s;
    if (threadIdx.x < 4) {
        hp[blockIdx.x * 4 + threadIdx.x] = 0.0f;
        hn[blockIdx.x * 4 + threadIdx.x] = __int_as_float(0x7F800000);
    }
    if (blockIdx.x == 0 && threadIdx.x == 0) *done = 0;
}

// 64x64 tile per wave, 4 independent waves/block, upper triangle (c>=r).
// 4x4 tiles of mfma_f32_16x16x32_bf16, K=512 in 16 k-tiles, register dbuf.
// Frag load: lane reads 16 B at row (base + t*16 + (lane&15)), k-off (lane>>4)*8.
__global__ __launch_bounds__(256, 2) void k_dist(const ushort* __restrict__ xhi,
                                                 const int* __restrict__ labels,
                                                 const float* __restrict__ norms,
                                                 float* __restrict__ hp,
                                                 float* __restrict__ hn,
                                                 int* __restrict__ done,
                                                 float* __restrict__ out) {
    const int lane = threadIdx.x & 63;
    const int wv = blockIdx.x * 4 + (threadIdx.x >> 6);  // wave-job id 0..2079

    // Triangular decode: wv -> (r, c), c >= r, 64x64 tile grid.
    int r = (int)((129.0f - sqrtf(16641.0f - 8.0f * (float)wv)) * 0.5f);
    int base = r * 64 - (r * (r - 1)) / 2;
    if (wv < base)                 { --r; base = r * 64 - (r * (r - 1)) / 2; }
    else if (wv >= base + 64 - r)  { ++r; base = r * 64 - (r * (r - 1)) / 2; }
    const int rb = r * 64;
    const int cb = (r + (wv - base)) * 64;
    const bool diag = (rb == cb);

    const int q = lane >> 4, fr = lane & 15;
    const ushort* pa = xhi + (size_t)(rb + fr) * ND + q * 8;
    const ushort* pb = xhi + (size_t)(cb + fr) * ND + q * 8;

    f32x4 acc[4][4];
    #pragma unroll
    for (int mi = 0; mi < 4; ++mi)
        #pragma unroll
        for (int ni = 0; ni < 4; ++ni)
            acc[mi][ni] = (f32x4){0.f, 0.f, 0.f, 0.f};

    short8 a0[4], b0[4], a1[4], b1[4];
    #define LOADF(dst_a, dst_b, kt)                                            \
        {                                                                      \
            _Pragma("unroll")                                                  \
            for (int mi = 0; mi < 4; ++mi) {                                   \
                dst_a[mi] = *(const short8*)(pa + (size_t)mi * 16 * ND + (kt) * 32); \
                dst_b[mi] = *(const short8*)(pb + (size_t)mi * 16 * ND + (kt) * 32); \
            }                                                                  \
        }
    #define MFMA16(aa, bb)                                                     \
        {                                                                      \
            _Pragma("unroll")                                                  \
            for (int mi = 0; mi < 4; ++mi)                                     \
                _Pragma("unroll")                                              \
                for (int ni = 0; ni < 4; ++ni)                                 \
                    acc[mi][ni] = __builtin_amdgcn_mfma_f32_16x16x32_bf16(     \
                        aa[mi], bb[ni], acc[mi][ni], 0, 0, 0);                 \
        }

    LOADF(a0, b0, 0)
    #pragma unroll
    for (int kt = 0; kt < 16; kt += 2) {
        if (kt + 1 < 16) LOADF(a1, b1, kt + 1)   // prefetch while computing kt
        MFMA16(a0, b0)
        if (kt + 2 < 16) LOADF(a0, b0, kt + 2)   // prefetch while computing kt+1
        MFMA16(a1, b1)
    }
    #undef LOADF
    #undef MFMA16

    // Epilogue. C/D layout: col = lane&15, row = (lane>>4)*4 + reg.
    int gcol[4]; float ncol[4]; int lcol[4];
    #pragma unroll
    for (int ni = 0; ni < 4; ++ni) {
        gcol[ni] = cb + ni * 16 + fr;
        ncol[ni] = norms[gcol[ni]];
        lcol[ni] = labels[gcol[ni]];
    }
    float pmc[4], nmc[4];
    #pragma unroll
    for (int ni = 0; ni < 4; ++ni) {
        pmc[ni] = 0.0f;
        nmc[ni] = __int_as_float(0x7F800000);
    }
    #pragma unroll
    for (int mi = 0; mi < 4; ++mi) {
        #pragma unroll
        for (int reg = 0; reg < 4; ++reg) {
            const int grow = rb + mi * 16 + q * 4 + reg;
            const float nr = norms[grow];
            const int lr = labels[grow];
            float pm = 0.0f, nm = __int_as_float(0x7F800000);
            #pragma unroll
            for (int ni = 0; ni < 4; ++ni) {
                float sq = fmaxf(nr + ncol[ni] - 2.0f * acc[mi][ni][reg], 0.0f);
                float dd = sqrtf(sq);
                if (lr == lcol[ni]) {
                    if (grow != gcol[ni]) {
                        pm = fmaxf(pm, dd);
                        pmc[ni] = fmaxf(pmc[ni], dd);
                    }
                } else {
                    nm = fminf(nm, dd);
                    nmc[ni] = fminf(nmc[ni], dd);
                }
            }
            #pragma unroll
            for (int m = 1; m <= 8; m <<= 1) {
                pm = fmaxf(pm, __shfl_xor(pm, m));
                nm = fminf(nm, __shfl_xor(nm, m));
            }
            if (fr == 0) {
                // Nonneg floats: int compare == float compare.
                atomicMax((int*)&hp[grow], __float_as_int(pm));
                atomicMin((int*)&hn[grow], __float_as_int(nm));
            }
        }
    }
    if (!diag) {  // diagonal tiles: col stats duplicate row stats by symmetry
        #pragma unroll
        for (int ni = 0; ni < 4; ++ni) {
            #pragma unroll
            for (int m = 16; m <= 32; m <<= 1) {
                pmc[ni] = fmaxf(pmc[ni], __shfl_xor(pmc[ni], m));
                nmc[ni] = fminf(nmc[ni], __shfl_xor(nmc[ni], m));
            }
            if (q == 0) {
                atomicMax((int*)&hp[gcol[ni]], __float_as_int(pmc[ni]));
                atomicMin((int*)&hn[gcol[ni]], __float_as_int(nmc[ni]));
            }
        }
    }

    // Last-wave finalize: release fence + counter; winner acquires and reduces.
    __threadfence();
    int lastFlag = 0;
    if (lane == 0) lastFlag = (atomicAdd(done, 1) == NTILE - 1) ? 1 : 0;
    lastFlag = __builtin_amdgcn_readfirstlane(lastFlag);
    if (lastFlag) {
        __threadfence();  // acquire side
        __shared__ int h[NLAB];
        h[lane] = 0;  // only this wave touches h; wave LDS ops are in order
        for (int i = lane; i < NB; i += 64) atomicAdd(&h[labels[i]], 1);
        float s = 0.0f;
        int c = 0;
        for (int i = lane; i < NB; i += 64) {
            const int k = h[labels[i]];
            if (k >= 2 && k < NB) {
                float av = __hip_atomic_load(&hp[i], __ATOMIC_RELAXED, __HIP_MEMORY_SCOPE_AGENT);
                float bv = __hip_atomic_load(&hn[i], __ATOMIC_RELAXED, __HIP_MEMORY_SCOPE_AGENT);
                s += fmaxf(av - bv + 0.5f, 0.0f);
                c += 1;
            }
        }
        #pragma unroll
        for (int m = 1; m < 64; m <<= 1) {
            s += __shfl_xor(s, m);
            c += __shfl_xor(c, m);
        }
        if (lane == 0) out[0] = (c > 0) ? (s / (float)c) : 0.0f;
    }
}

extern "C" void kernel_launch(void* const* d_in, const int* in_sizes, int n_in,
                              void* d_out, int out_size, void* d_ws, size_t ws_size,
                              hipStream_t stream) {
    const float* x      = (const float*)d_in[0];
    const int*   labels = (const int*)d_in[1];
    float* ws    = (float*)d_ws;
    float* hp    = ws;
    float* hn    = ws + NB;
    float* norms = ws + 2 * NB;
    int*   done  = (int*)(ws + 3 * NB);
    ushort* xhi  = (ushort*)(ws + 4 * NB);   // 4 MB bf16 matrix
    float* out   = (float*)d_out;

    k_prep<<<dim3(NB / 4), dim3(256), 0, stream>>>(x, xhi, norms, hp, hn, done);
    k_dist<<<dim3(NTILE / 4), dim3(256), 0, stream>>>(xhi, labels, norms, hp, hn, done, out);
}

// Round 12
// 150.315 us; speedup vs baseline: 1.1369x; 1.1369x over previous
//
#include <hip/hip_runtime.h>
#include <math.h>

// HardTripletLoss: B=4096, D=512, labels in [0,64), margin 0.5, scalar fp32 out.
// R8 (4th resubmit after infra timeouts): 128x128 triangle tiles (528 blocks, 4
// waves, 64x64 quadrants), BK=32, TRIPLE-buffered LDS with partial-drain
// barriers: "s_waitcnt vmcnt(4); s_barrier" keeps the newest STAGE in flight
// across the barrier (AITER pattern). STAGE(k) gets ~2 compute phases to land.
// Finalize fused via per-wave done counter.
//
// ws layout (floats): [0,4096)=hp, [4096,8192)=hn, [8192,12288)=norms,
//                     [12288]=done(int), [16384, +2M ushorts)=xhi (4 MB)

#define NB 4096
#define ND 512
#define NLAB 64
#define NWORK 2112  // 528 blocks * 4 waves: done-counter target

typedef __attribute__((ext_vector_type(8))) short short8;
typedef __attribute__((ext_vector_type(4))) float f32x4;

__device__ __forceinline__ ushort bf16rn(float f) {
    unsigned u = __float_as_uint(f);
    u += 0x7FFF + ((u >> 16) & 1);  // round-to-nearest-even
    return (ushort)(u >> 16);
}

__device__ __forceinline__ void gload_lds16(const ushort* g, ushort* l) {
    __builtin_amdgcn_global_load_lds(
        (const __attribute__((address_space(1))) void*)g,
        (__attribute__((address_space(3))) void*)l, 16, 0, 0);
}

// One wave per row: fp32->bf16 convert + exact fp32 norm; init hp/hn; zero done.
__global__ __launch_bounds__(256) void k_prep(const float* __restrict__ x,
                                              ushort* __restrict__ xhi,
                                              float* __restrict__ norms,
                                              float* __restrict__ hp,
                                              float* __restrict__ hn,
                                              int* __restrict__ done) {
    const int wave = threadIdx.x >> 6, lane = threadIdx.x & 63;
    const int row = blockIdx.x * 4 + wave;
    const float* p = x + (size_t)row * ND + lane * 8;
    float4 v0 = *(const float4*)p;
    float4 v1 = *(const float4*)(p + 4);
    ushort h[8];
    h[0] = bf16rn(v0.x); h[1] = bf16rn(v0.y); h[2] = bf16rn(v0.z); h[3] = bf16rn(v0.w);
    h[4] = bf16rn(v1.x); h[5] = bf16rn(v1.y); h[6] = bf16rn(v1.z); h[7] = bf16rn(v1.w);
    *(uint4*)(xhi + (size_t)row * ND + lane * 8) = *(const uint4*)h;
    float s = v0.x*v0.x + v0.y*v0.y + v0.z*v0.z + v0.w*v0.w
            + v1.x*v1.x + v1.y*v1.y + v1.z*v1.z + v1.w*v1.w;
    #pragma unroll
    for (int m = 1; m < 64; m <<= 1) s += __shfl_xor(s, m);
    if (lane == 0) norms[row] = s;
    if (threadIdx.x < 4) {
        hp[blockIdx.x * 4 + threadIdx.x] = 0.0f;
        hn[blockIdx.x * 4 + threadIdx.x] = __int_as_float(0x7F800000);
    }
    if (blockIdx.x == 0 && threadIdx.x == 0) *done = 0;
}

__global__ __launch_bounds__(256, 2) void k_dist(const ushort* __restrict__ xhi,
                                                 const int* __restrict__ labels,
                                                 const float* __restrict__ norms,
                                                 float* __restrict__ hp,
                                                 float* __restrict__ hn,
                                                 int* __restrict__ done,
                                                 float* __restrict__ out) {
    // 3 buffers x (A 128x32 + B 128x32) bf16 = 48 KB.
    __shared__ ushort As0[128 * 32], As1[128 * 32], As2[128 * 32];
    __shared__ ushort Bs0[128 * 32], Bs1[128 * 32], Bs2[128 * 32];

    // Triangular decode: bid -> (r, c), c >= r, 32x32 tile grid (528 blocks).
    const int bid = blockIdx.x;
    int r = (int)((65.0f - sqrtf(4225.0f - 8.0f * (float)bid)) * 0.5f);
    int base = r * 32 - (r * (r - 1)) / 2;
    if (bid < base)                { --r; base = r * 32 - (r * (r - 1)) / 2; }
    else if (bid >= base + 32 - r) { ++r; base = r * 32 - (r * (r - 1)) / 2; }
    const int rb = r * 128;
    const int cb = (r + (bid - base)) * 128;
    const bool diag = (rb == cb);

    const int tid = threadIdx.x;
    const int w = tid >> 6, lane = tid & 63;
    const int wr = (w >> 1) * 64, wc = (w & 1) * 64;   // 64x64 quadrant
    const int q = lane >> 4, fr = lane & 15;
    const int srow = lane >> 2, sch = lane & 3;        // staging: 16 rows x 4 chunks

    // Wave w stages rows [w*32, w*32+32) of A and B: 2+2 gload_lds16 per STAGE.
    const ushort* gA = xhi + (size_t)(rb + w * 32 + srow) * ND + sch * 8;
    const ushort* gB = xhi + (size_t)(cb + w * 32 + srow) * ND + sch * 8;
    const int ldsw = w * 1024;  // ushort offset of this wave's 32-row slab

    f32x4 acc[4][4];
    #pragma unroll
    for (int mi = 0; mi < 4; ++mi)
        #pragma unroll
        for (int ni = 0; ni < 4; ++ni)
            acc[mi][ni] = (f32x4){0.f, 0.f, 0.f, 0.f};

    // ko = k-chunk offset in ushorts (chunk k -> k*32).
    #define STAGE(Ad, Bd, ko)                                   \
        {                                                       \
            gload_lds16(gA + (ko), (Ad) + ldsw);                \
            gload_lds16(gA + 16 * ND + (ko), (Ad) + ldsw + 512);\
            gload_lds16(gB + (ko), (Bd) + ldsw);                \
            gload_lds16(gB + 16 * ND + (ko), (Bd) + ldsw + 512);\
        }

    #define COMPUTE(Ab_, Bb_)                                                  \
        {                                                                      \
            short8 a[4], b[4];                                                 \
            _Pragma("unroll")                                                  \
            for (int mi = 0; mi < 4; ++mi)                                     \
                a[mi] = *(const short8*)((Ab_) + (wr + mi * 16 + fr) * 32 + q * 8); \
            _Pragma("unroll")                                                  \
            for (int ni = 0; ni < 4; ++ni)                                     \
                b[ni] = *(const short8*)((Bb_) + (wc + ni * 16 + fr) * 32 + q * 8); \
            _Pragma("unroll")                                                  \
            for (int mi = 0; mi < 4; ++mi)                                     \
                _Pragma("unroll")                                              \
                for (int ni = 0; ni < 4; ++ni)                                 \
                    acc[mi][ni] = __builtin_amdgcn_mfma_f32_16x16x32_bf16(     \
                        a[mi], b[ni], acc[mi][ni], 0, 0, 0);                   \
        }

    // Partial-drain barrier: drains STAGE(k) (oldest 4), leaves STAGE(k+1)
    // (newest 4) in flight across the barrier. Tail barrier drains all.
    #define BAR4 asm volatile("s_waitcnt vmcnt(4) lgkmcnt(0)\n\ts_barrier" ::: "memory")
    #define BAR0 asm volatile("s_waitcnt vmcnt(0) lgkmcnt(0)\n\ts_barrier" ::: "memory")
    // Iter k (k<14): drain STAGE(k), stage chunk k+2 into buf (k+2)%3
    // (last read at iter k-1, protected by this barrier), compute chunk k.
    #define ITER(Ac, Bc, Sa, Sb, ko) BAR4; STAGE(Sa, Sb, ko) COMPUTE(Ac, Bc)

    STAGE(As0, Bs0, 0 * 32)
    STAGE(As1, Bs1, 1 * 32)
    ITER(As0, Bs0, As2, Bs2,  2 * 32)   // k=0
    ITER(As1, Bs1, As0, Bs0,  3 * 32)   // k=1
    ITER(As2, Bs2, As1, Bs1,  4 * 32)   // k=2
    ITER(As0, Bs0, As2, Bs2,  5 * 32)   // k=3
    ITER(As1, Bs1, As0, Bs0,  6 * 32)   // k=4
    ITER(As2, Bs2, As1, Bs1,  7 * 32)   // k=5
    ITER(As0, Bs0, As2, Bs2,  8 * 32)   // k=6
    ITER(As1, Bs1, As0, Bs0,  9 * 32)   // k=7
    ITER(As2, Bs2, As1, Bs1, 10 * 32)   // k=8
    ITER(As0, Bs0, As2, Bs2, 11 * 32)   // k=9
    ITER(As1, Bs1, As0, Bs0, 12 * 32)   // k=10
    ITER(As2, Bs2, As1, Bs1, 13 * 32)   // k=11
    ITER(As0, Bs0, As2, Bs2, 14 * 32)   // k=12
    ITER(As1, Bs1, As0, Bs0, 15 * 32)   // k=13
    BAR4; COMPUTE(As2, Bs2)             // k=14: drain STAGE(14), 15 in flight
    BAR0; COMPUTE(As0, Bs0)             // k=15: drain STAGE(15)
    #undef ITER
    #undef BAR4
    #undef BAR0
    #undef STAGE
    #undef COMPUTE

    // Epilogue. C/D layout: col = lane&15, row = (lane>>4)*4 + reg.
    int gcol[4]; float ncol[4]; int lcol[4];
    #pragma unroll
    for (int ni = 0; ni < 4; ++ni) {
        gcol[ni] = cb + wc + ni * 16 + fr;
        ncol[ni] = norms[gcol[ni]];
        lcol[ni] = labels[gcol[ni]];
    }
    float pmc[4], nmc[4];
    #pragma unroll
    for (int ni = 0; ni < 4; ++ni) {
        pmc[ni] = 0.0f;
        nmc[ni] = __int_as_float(0x7F800000);
    }
    #pragma unroll
    for (int mi = 0; mi < 4; ++mi) {
        #pragma unroll
        for (int reg = 0; reg < 4; ++reg) {
            const int grow = rb + wr + mi * 16 + q * 4 + reg;
            const float nr = norms[grow];
            const int lr = labels[grow];
            float pm = 0.0f, nm = __int_as_float(0x7F800000);
            #pragma unroll
            for (int ni = 0; ni < 4; ++ni) {
                float sq = fmaxf(nr + ncol[ni] - 2.0f * acc[mi][ni][reg], 0.0f);
                float dd = sqrtf(sq);
                if (lr == lcol[ni]) {
                    if (grow != gcol[ni]) {
                        pm = fmaxf(pm, dd);
                        pmc[ni] = fmaxf(pmc[ni], dd);
                    }
                } else {
                    nm = fminf(nm, dd);
                    nmc[ni] = fminf(nmc[ni], dd);
                }
            }
            #pragma unroll
            for (int m = 1; m <= 8; m <<= 1) {
                pm = fmaxf(pm, __shfl_xor(pm, m));
                nm = fminf(nm, __shfl_xor(nm, m));
            }
            if (fr == 0) {
                // Nonneg floats: int compare == float compare.
                atomicMax((int*)&hp[grow], __float_as_int(pm));
                atomicMin((int*)&hn[grow], __float_as_int(nm));
            }
        }
    }
    if (!diag) {  // diagonal tiles: col stats duplicate row stats by symmetry
        #pragma unroll
        for (int ni = 0; ni < 4; ++ni) {
            #pragma unroll
            for (int m = 16; m <= 32; m <<= 1) {
                pmc[ni] = fmaxf(pmc[ni], __shfl_xor(pmc[ni], m));
                nmc[ni] = fminf(nmc[ni], __shfl_xor(nmc[ni], m));
            }
            if (q == 0) {
                atomicMax((int*)&hp[gcol[ni]], __float_as_int(pmc[ni]));
                atomicMin((int*)&hn[gcol[ni]], __float_as_int(nmc[ni]));
            }
        }
    }

    // Per-wave done increment (each wave's threadfence covers its OWN atomics);
    // the NWORK-th wave knows all hp/hn updates are globally visible.
    __threadfence();
    int lastFlag = 0;
    if (lane == 0) lastFlag = (atomicAdd(done, 1) == NWORK - 1) ? 1 : 0;
    lastFlag = __builtin_amdgcn_readfirstlane(lastFlag);
    if (lastFlag) {
        __threadfence();  // acquire side
        __shared__ int h[NLAB];
        h[lane & (NLAB - 1)] = 0;  // single wave: LDS ops in program order
        for (int i = lane; i < NB; i += 64) atomicAdd(&h[labels[i]], 1);
        float s = 0.0f;
        int c = 0;
        for (int i = lane; i < NB; i += 64) {
            const int k = h[labels[i]];
            if (k >= 2 && k < NB) {
                float av = __hip_atomic_load(&hp[i], __ATOMIC_RELAXED, __HIP_MEMORY_SCOPE_AGENT);
                float bv = __hip_atomic_load(&hn[i], __ATOMIC_RELAXED, __HIP_MEMORY_SCOPE_AGENT);
                s += fmaxf(av - bv + 0.5f, 0.0f);
                c += 1;
            }
        }
        #pragma unroll
        for (int m = 1; m < 64; m <<= 1) {
            s += __shfl_xor(s, m);
            c += __shfl_xor(c, m);
        }
        if (lane == 0) out[0] = (c > 0) ? (s / (float)c) : 0.0f;
    }
}

extern "C" void kernel_launch(void* const* d_in, const int* in_sizes, int n_in,
                              void* d_out, int out_size, void* d_ws, size_t ws_size,
                              hipStream_t stream) {
    const float* x      = (const float*)d_in[0];
    const int*   labels = (const int*)d_in[1];
    float* ws    = (float*)d_ws;
    float* hp    = ws;
    float* hn    = ws + NB;
    float* norms = ws + 2 * NB;
    int*   done  = (int*)(ws + 3 * NB);
    ushort* xhi  = (ushort*)(ws + 4 * NB);   // 4 MB bf16 matrix
    float* out   = (float*)d_out;

    k_prep<<<dim3(NB / 4), dim3(256), 0, stream>>>(x, xhi, norms, hp, hn, done);
    k_dist<<<dim3(528), dim3(256), 0, stream>>>(xhi, labels, norms, hp, hn, done, out);
}